// Round 7
// baseline (964.992 us; speedup 1.0000x reference)
//
#include <hip/hip_runtime.h>

#define V 30000
#define E 100
#define H 100
#define T 9
#define B 256
#define S 512

typedef float v2f __attribute__((ext_vector_type(2)));

__device__ __forceinline__ float fast_rcp(float x) { return __builtin_amdgcn_rcpf(x); }

template <int PAT>
__device__ __forceinline__ float dpp_mov(float x) {
  int t = __builtin_amdgcn_update_dpp(0, __builtin_bit_cast(int, x), PAT, 0xF, 0xF, true);
  return __builtin_bit_cast(float, t);
}

// Barrier that waits ONLY the LDS/SMEM counter — does NOT drain vmcnt, so
// register-resident global prefetches stay in flight across the barrier.
// (__syncthreads emits s_waitcnt vmcnt(0) lgkmcnt(0) and stalls the whole CU
// on the P-gather every step.)
__device__ __forceinline__ void barrier_lds_only() {
  __asm__ volatile("s_waitcnt lgkmcnt(0)\n\ts_barrier" ::: "memory");
}

// ---------------------------------------------------------------------------
// Kernel 1: P_d = embed @ Wih_d^T + b_d, PERMUTED columns:
//   P'[v][4*j + q] = P[v][q*100 + j]  (q = gate, j = unit)
// ---------------------------------------------------------------------------
#define LDE 72

__global__ __launch_bounds__(256) void precompute_P(
    const float* __restrict__ embed,
    const float* __restrict__ Wih_f, const float* __restrict__ b_f,
    const float* __restrict__ Wih_b, const float* __restrict__ b_b,
    float* __restrict__ Pf, float* __restrict__ Pb)
{
  __shared__ __align__(16) float eT[100 * LDE];
  __shared__ __align__(16) float wT[100 * LDE];
  int tid = threadIdx.x;
  int o0 = blockIdx.x * 64;
  int v0 = blockIdx.y * 64;

  for (int idx = tid; idx < 64 * 100; idx += 256) {
    int k = idx % 100, vi = idx / 100;
    int v = v0 + vi;
    eT[k * LDE + vi] = (v < V) ? embed[v * E + k] : 0.0f;
  }
  for (int idx = tid; idx < 64 * 100; idx += 256) {
    int k = idx % 100, oi = idx / 100;
    int o = o0 + oi;
    float val = 0.0f;
    if (o < 400) val = Wih_f[o * E + k];
    else if (o < 800) val = Wih_b[(o - 400) * E + k];
    wT[k * LDE + oi] = val;
  }
  __syncthreads();

  int tx = tid & 15, ty = tid >> 4;
  int vi0 = ty * 4, oi0 = tx * 4;
  float acc[4][4];
#pragma unroll
  for (int i = 0; i < 4; i++)
#pragma unroll
    for (int j = 0; j < 4; j++) acc[i][j] = 0.f;

  for (int k = 0; k < 100; k++) {
    float4 ev = *(const float4*)&eT[k * LDE + vi0];
    float4 wv = *(const float4*)&wT[k * LDE + oi0];
    float e[4] = {ev.x, ev.y, ev.z, ev.w};
    float w[4] = {wv.x, wv.y, wv.z, wv.w};
#pragma unroll
    for (int i = 0; i < 4; i++)
#pragma unroll
      for (int j = 0; j < 4; j++) acc[i][j] += e[i] * w[j];
  }

  for (int i = 0; i < 4; i++) {
    int v = v0 + vi0 + i;
    if (v >= V) break;
    for (int j = 0; j < 4; j++) {
      int o = o0 + oi0 + j;
      if (o >= 800) continue;
      int oo = (o < 400) ? o : (o - 400);
      int perm = 4 * (oo % 100) + (oo / 100);
      float bias = (o < 400) ? b_f[oo] : b_b[oo];
      float* dst = (o < 400) ? Pf : Pb;
      dst[(size_t)v * 400 + perm] = acc[i][j] + bias;
    }
  }
}

// ---------------------------------------------------------------------------
// Kernel 2: LSTM recurrence. One (dir,row) chain per block; 512 blocks,
// block = 512 threads (8 waves), 2 blocks/CU. Per-step barrier waits
// lgkmcnt ONLY (see barrier_lds_only) so the register P-prefetch spans it.
// ---------------------------------------------------------------------------
__global__ __attribute__((amdgpu_flat_work_group_size(512, 512), amdgpu_waves_per_eu(4, 4)))
void lstm_kernel(
    const int* __restrict__ x,
    const float* __restrict__ Pf, const float* __restrict__ Pb,
    const float* __restrict__ Whh_f, const float* __restrict__ Whh_b,
    const float* __restrict__ Wlin,
    float* __restrict__ em_f, float* __restrict__ em_b)
{
  __shared__ __align__(16) float h_lds[2][104];
  __shared__ int   x_lds[S];
  __shared__ float em_lds[S * T];

  int tid = threadIdx.x;
  int dir = blockIdx.x & 1;
  int b   = blockIdx.x >> 1;

  const float* P   = dir ? Pb : Pf;
  const float* Whh = dir ? Whh_b : Whh_f;
  float*       em  = dir ? em_b : em_f;

  bool is_mv = (tid < 400);
  int  og = tid >> 2, kq = tid & 3;
  bool lo2  = (kq < 2);
  bool oddl = (kq & 1);

  bool is_em = (tid >= 448 && tid < 448 + 4 * T);
  int  et = tid - 448;
  int  etag = et >> 2, ekq = et & 3;

  float mexp = (kq == 2) ? -2.f : -1.f;
  float sA   = (kq == 2) ?  2.f :  1.f;
  float sB   = (kq == 2) ? -1.f :  0.f;

  v2f  w2[4][12];
  float wr[4];
  if (is_mv) {
#pragma unroll
    for (int q = 0; q < 4; q++) {
      const float* row = &Whh[(size_t)(q * 100 + og) * 100];
#pragma unroll
      for (int i = 0; i < 6; i++) {
        float4 t4 = *(const float4*)&row[24 * kq + 4 * i];
        w2[q][2 * i]     = (v2f){t4.x, t4.y};
        w2[q][2 * i + 1] = (v2f){t4.z, t4.w};
      }
      wr[q] = row[96 + kq];
    }
  } else if (is_em) {
    const float* row = &Wlin[etag * (2 * H) + dir * H];
#pragma unroll
    for (int i = 0; i < 6; i++) {
      float4 t4 = *(const float4*)&row[24 * ekq + 4 * i];
      w2[0][2 * i]     = (v2f){t4.x, t4.y};
      w2[0][2 * i + 1] = (v2f){t4.z, t4.w};
    }
    wr[0] = row[96 + ekq];
  }

  for (int i = tid; i < 208; i += 512) ((float*)h_lds)[i] = 0.f;
  for (int i = tid; i < S; i += 512) x_lds[i] = x[(size_t)b * S + i];
  float c = 0.f;
  float pre = 0.f;
  if (is_mv) {
    int tt0 = dir ? (S - 1) : 0;
    pre = P[(size_t)x[(size_t)b * S + tt0] * 400 + tid];
  }
  int prev_tt = 0;
  __syncthreads();

  auto step = [&](int bufc, int t) {
    int tt = dir ? (S - 1 - t) : t;
    if (is_mv) {
      float prv = pre;
      if (t + 1 < S) {
        int ttn = dir ? (S - 2 - t) : (t + 1);
        int xv = x_lds[ttn];
        unsigned sxv = __builtin_amdgcn_readfirstlane(xv);
        const float* rowp = P + (size_t)sxv * 400;
        pre = rowp[tid];
      }
      const float* hq = &h_lds[bufc][24 * kq];
      v2f a0 = {0.f, 0.f}, a1 = {0.f, 0.f}, a2 = {0.f, 0.f}, a3 = {0.f, 0.f};
#pragma unroll
      for (int i = 0; i < 6; i++) {
        float4 h4 = *(const float4*)&hq[4 * i];
        v2f hlo = {h4.x, h4.y}, hhi = {h4.z, h4.w};
        a0 = __builtin_elementwise_fma(w2[0][2 * i], hlo, a0);
        a0 = __builtin_elementwise_fma(w2[0][2 * i + 1], hhi, a0);
        a1 = __builtin_elementwise_fma(w2[1][2 * i], hlo, a1);
        a1 = __builtin_elementwise_fma(w2[1][2 * i + 1], hhi, a1);
        a2 = __builtin_elementwise_fma(w2[2][2 * i], hlo, a2);
        a2 = __builtin_elementwise_fma(w2[2][2 * i + 1], hhi, a2);
        a3 = __builtin_elementwise_fma(w2[3][2 * i], hlo, a3);
        a3 = __builtin_elementwise_fma(w2[3][2 * i + 1], hhi, a3);
      }
      float hr = h_lds[bufc][96 + kq];
      float p0 = fmaf(wr[0], hr, a0.x + a0.y);
      float p1 = fmaf(wr[1], hr, a1.x + a1.y);
      float p2 = fmaf(wr[2], hr, a2.x + a2.y);
      float p3 = fmaf(wr[3], hr, a3.x + a3.y);

      float u  = lo2 ? p2 : p0;
      float v  = lo2 ? p3 : p1;
      float ru = dpp_mov<0x4E>(u);
      float rv = dpp_mov<0x4E>(v);
      float A  = (lo2 ? p0 : p2) + ru;
      float Bv = (lo2 ? p1 : p3) + rv;
      float wv = oddl ? A : Bv;
      float rw = dpp_mov<0xB1>(wv);
      float g  = (oddl ? Bv : A) + rw + prv;

      float e   = __expf(mexp * g);
      float act = fmaf(sA, fast_rcp(1.f + e), sB);

      float gi = dpp_mov<0x00>(act);
      float gf = dpp_mov<0x55>(act);
      float tg = dpp_mov<0xAA>(act);
      float go = dpp_mov<0xFF>(act);

      c = fmaf(gf, c, gi * tg);
      float th = fmaf(2.f, fast_rcp(1.f + __expf(-2.f * c)), -1.f);
      if (kq == 0) h_lds[bufc ^ 1][og] = go * th;
    } else if (is_em && t > 0) {
      const float* hq = &h_lds[bufc][24 * ekq];
      v2f a = {0.f, 0.f};
#pragma unroll
      for (int i = 0; i < 6; i++) {
        float4 h4 = *(const float4*)&hq[4 * i];
        a = __builtin_elementwise_fma(w2[0][2 * i], (v2f){h4.x, h4.y}, a);
        a = __builtin_elementwise_fma(w2[0][2 * i + 1], (v2f){h4.z, h4.w}, a);
      }
      float hr = h_lds[bufc][96 + ekq];
      float p = fmaf(wr[0], hr, a.x + a.y);
      p += dpp_mov<0xB1>(p);
      p += dpp_mov<0x4E>(p);
      if (ekq == 0) em_lds[prev_tt * T + etag] = p;
    }
    barrier_lds_only();
    prev_tt = tt;
  };

  for (int t = 0; t < S; t += 2) {
    step(0, t);
    step(1, t + 1);
  }

  if (is_em) {
    const float* hq = &h_lds[0][24 * ekq];
    v2f a = {0.f, 0.f};
#pragma unroll
    for (int i = 0; i < 6; i++) {
      float4 h4 = *(const float4*)&hq[4 * i];
      a = __builtin_elementwise_fma(w2[0][2 * i], (v2f){h4.x, h4.y}, a);
      a = __builtin_elementwise_fma(w2[0][2 * i + 1], (v2f){h4.z, h4.w}, a);
    }
    float hr = h_lds[0][96 + ekq];
    float p = fmaf(wr[0], hr, a.x + a.y);
    p += dpp_mov<0xB1>(p);
    p += dpp_mov<0x4E>(p);
    if (ekq == 0) em_lds[prev_tt * T + etag] = p;
  }
  __syncthreads();

  float* dst = em + (size_t)b * S * T;
  for (int i = tid; i < S * T; i += 512) dst[i] = em_lds[i];
}

// ---------------------------------------------------------------------------
// Kernel 3: Viterbi. em preloaded to LDS; the 9 cross-lane score reads are
// HOISTED into registers before any use so the 9 ds_bpermute latencies
// pipeline (interleaved use serialized them: ~9x120 cyc/step).
// ---------------------------------------------------------------------------
__global__ __launch_bounds__(64) void viterbi_kernel(
    const float* __restrict__ em_f, const float* __restrict__ em_b,
    const float* __restrict__ blin, const float* __restrict__ start,
    const float* __restrict__ trans, const float* __restrict__ endv,
    float* __restrict__ out)
{
  __shared__ float ev[S * 12];
  __shared__ unsigned char bp[S * T];
  int b = blockIdx.x;
  int lane = threadIdx.x;
  bool act = (lane < T);
  int tag = act ? lane : 0;

  const float* ef = em_f + (size_t)b * S * T;
  const float* eb = em_b + (size_t)b * S * T;
  for (int i = lane; i < S * T; i += 64) {
    int t = i / 9, tg = i - t * 9;
    ev[t * 12 + tg] = ef[i] + eb[i] + blin[tg];
  }
  __syncthreads();

  float tc[T] = {};
  float en = 0.f;
  float score = -1e30f;
  if (act) {
    for (int p = 0; p < T; p++) tc[p] = trans[p * T + tag];
    en = endv[tag];
    score = start[tag] + ev[tag];
  }

  for (int t = 1; t < S; t++) {
    float emv = act ? ev[t * 12 + tag] : 0.f;

    float sv[T];
#pragma unroll
    for (int p = 0; p < T; p++) sv[p] = __shfl(score, p);   // batched: waits pipeline

    float best = sv[0] + tc[0]; int bestp = 0;
#pragma unroll
    for (int p = 1; p < T; p++) {
      float cand = sv[p] + tc[p];
      if (cand > best) { best = cand; bestp = p; }   // strict '>' = first-max
    }
    if (act) {
      score = best + emv;
      bp[t * T + tag] = (unsigned char)bestp;
    }
  }
  if (act) score += en;
  __syncthreads();

  float sv[T];
#pragma unroll
  for (int p = 0; p < T; p++) sv[p] = __shfl(score, p);
  float bs = sv[0]; int last = 0;
#pragma unroll
  for (int p = 1; p < T; p++) {
    if (sv[p] > bs) { bs = sv[p]; last = p; }
  }

  if (lane == 0) {
    out[(size_t)B * S + b] = bs;
    int cur = last;
    out[(size_t)b * S + (S - 1)] = (float)cur;
    for (int t = S - 1; t >= 1; t--) {
      cur = bp[t * T + cur];
      out[(size_t)b * S + (t - 1)] = (float)cur;
    }
  }
}

// ---------------------------------------------------------------------------
extern "C" void kernel_launch(void* const* d_in, const int* in_sizes, int n_in,
                              void* d_out, int out_size, void* d_ws, size_t ws_size,
                              hipStream_t stream)
{
  const int*   x     = (const int*)d_in[0];
  const float* embed = (const float*)d_in[2];
  const float* Wih_f = (const float*)d_in[3];
  const float* Whh_f = (const float*)d_in[4];
  const float* b_f   = (const float*)d_in[5];
  const float* Wih_b = (const float*)d_in[6];
  const float* Whh_b = (const float*)d_in[7];
  const float* b_b   = (const float*)d_in[8];
  const float* Wlin  = (const float*)d_in[9];
  const float* blin  = (const float*)d_in[10];
  const float* start = (const float*)d_in[11];
  const float* trans = (const float*)d_in[12];
  const float* endv  = (const float*)d_in[13];
  float* out = (float*)d_out;

  char* ws = (char*)d_ws;
  float* Pf   = (float*)ws;  ws += (size_t)V * 400 * sizeof(float);
  float* Pb   = (float*)ws;  ws += (size_t)V * 400 * sizeof(float);
  float* emf  = (float*)ws;  ws += (size_t)B * S * T * sizeof(float);
  float* emb_ = (float*)ws;  ws += (size_t)B * S * T * sizeof(float);

  precompute_P<<<dim3(13, 469), 256, 0, stream>>>(embed, Wih_f, b_f, Wih_b, b_b, Pf, Pb);
  lstm_kernel<<<dim3(512), 512, 0, stream>>>(x, Pf, Pb, Whh_f, Whh_b, Wlin, emf, emb_);
  viterbi_kernel<<<dim3(256), 64, 0, stream>>>(emf, emb_, blin, start, trans, endv, out);
}